// Round 1
// baseline (567.823 us; speedup 1.0000x reference)
//
#include <hip/hip_runtime.h>
#include <stdint.h>

#define D_MODEL 512
#define D_STATE 16
#define DT_RANK 32
#define SEQ 2048
#define NBATCH 4
#define FN 32

typedef unsigned short u16;
using s16x8 = __attribute__((ext_vector_type(8))) short;
using f32x4 = __attribute__((ext_vector_type(4))) float;

__device__ inline u16 f2bf(float f) {
  uint32_t u = __float_as_uint(f);
  u += 0x7FFFu + ((u >> 16) & 1u);   // RNE
  return (u16)(u >> 16);
}

// ---------------- FiLM params: gamma/beta per batch ----------------
__global__ __launch_bounds__(512) void film_kernel(
    const float* __restrict__ gpt, const float* __restrict__ w1, const float* __restrict__ b1,
    const float* __restrict__ w2, const float* __restrict__ b2, float* __restrict__ gb)
{
  int b = blockIdx.x; int t = threadIdx.x;
  __shared__ float g[D_MODEL];
  __shared__ float h[D_MODEL];
  g[t] = gpt[b*D_MODEL + t];
  __syncthreads();
  float s = b1[t];
  const float* wr = &w1[(size_t)t*D_MODEL];
  #pragma unroll 4
  for (int k = 0; k < D_MODEL; k += 4) {
    float4 w = *(const float4*)&wr[k];
    s += w.x*g[k] + w.y*g[k+1] + w.z*g[k+2] + w.w*g[k+3];
  }
  h[t] = s / (1.f + expf(-s));   // silu
  __syncthreads();
  #pragma unroll
  for (int o = 0; o < 2; o++) {
    int row = t + o*D_MODEL;
    float s2 = b2[row];
    const float* wr2 = &w2[(size_t)row*D_MODEL];
    #pragma unroll 4
    for (int k = 0; k < D_MODEL; k += 4) {
      float4 w = *(const float4*)&wr2[k];
      s2 += w.x*h[k] + w.y*h[k+1] + w.z*h[k+2] + w.w*h[k+3];
    }
    gb[b*(2*D_MODEL) + row] = s2;
  }
}

// ---------------- cross-attn + FiLM, writes x as bf16 ----------------
__global__ __launch_bounds__(256) void xattn_kernel(
    const float* __restrict__ atoms, const float* __restrict__ fg,
    const float* __restrict__ gb, u16* __restrict__ xout)
{
  int l = blockIdx.x, b = blockIdx.y;
  size_t row = (size_t)b*SEQ + l;
  const float* arow = &atoms[row*D_MODEL];
  __shared__ float a_s[D_MODEL];
  __shared__ float sc[FN];
  __shared__ float attn_s[FN];
  int t = threadIdx.x;
  *(float2*)&a_s[t*2] = *(const float2*)&arow[t*2];
  __syncthreads();
  int f = t >> 3, sub = t & 7;
  {
    const float* fgrow = &fg[((size_t)b*FN + f)*D_MODEL + sub*64];
    const float* as = &a_s[sub*64];
    float s = 0.f;
    #pragma unroll 4
    for (int k = 0; k < 64; k += 4) {
      float4 w = *(const float4*)&fgrow[k];
      s += w.x*as[k] + w.y*as[k+1] + w.z*as[k+2] + w.w*as[k+3];
    }
    s += __shfl_down(s, 4); s += __shfl_down(s, 2); s += __shfl_down(s, 1);
    if (sub == 0) sc[f] = s * 0.04419417382415922f;  // 1/sqrt(512)
  }
  __syncthreads();
  if (t < FN) {
    float v = sc[t]; float m = v;
    #pragma unroll
    for (int o = 16; o; o >>= 1) m = fmaxf(m, __shfl_xor(m, o, FN));
    float e = expf(v - m); float sum = e;
    #pragma unroll
    for (int o = 16; o; o >>= 1) sum += __shfl_xor(sum, o, FN);
    attn_s[t] = e / sum;
  }
  __syncthreads();
  #pragma unroll
  for (int rep = 0; rep < 2; rep++) {
    int d = t + rep*256;
    float acc = a_s[d];
    #pragma unroll 8
    for (int f2 = 0; f2 < FN; f2++)
      acc += attn_s[f2] * fg[((size_t)b*FN + f2)*D_MODEL + d];
    float gamma = gb[b*1024 + d], beta = gb[b*1024 + D_MODEL + d];
    xout[row*D_MODEL + d] = f2bf(acc*gamma + beta);
  }
}

// ---------------- f32 -> bf16 convert ----------------
__global__ __launch_bounds__(256) void cvt_bf16_kernel(
    const float* __restrict__ in, u16* __restrict__ out, int n4)
{
  int i = blockIdx.x*256 + threadIdx.x;
  if (i >= n4) return;
  float4 v = *(const float4*)&in[(size_t)i*4];
  ushort4 o; o.x = f2bf(v.x); o.y = f2bf(v.y); o.z = f2bf(v.z); o.w = f2bf(v.w);
  *(ushort4*)&out[(size_t)i*4] = o;
}

// ---------------- bf16 GEMM: C[M][N] = A[M][K] @ Bt[N][K]^T, fp32 out ----------------
__global__ __launch_bounds__(256) void gemm_bt_kernel(
    const u16* __restrict__ Ag, const u16* __restrict__ Bg, float* __restrict__ Cg,
    int M, int N, int K, long long azs, long long bzs, long long czs, int clampFinite)
{
  const u16* A = Ag + (size_t)blockIdx.z * azs;
  const u16* B = Bg + (size_t)blockIdx.z * bzs;
  float* C = Cg + (size_t)blockIdx.z * czs;
  int m0 = blockIdx.y * 128, n0 = blockIdx.x * 128;
  __shared__ u16 As[128][32];
  __shared__ u16 Bs[128][32];
  int tid = threadIdx.x, lane = tid & 63, wave = tid >> 6;
  int wm = (wave >> 1) * 64, wn = (wave & 1) * 64;
  int fr = lane & 15, fk = (lane >> 4) * 8;
  int srow = tid >> 2, scol = (tid & 3) * 8;
  f32x4 acc[4][4] = {};
  const size_t lda = K, ldb = K;
  for (int k0 = 0; k0 < K; k0 += 32) {
    *(s16x8*)(&As[srow][scol])      = *(const s16x8*)(&A[(size_t)(m0 + srow)*lda + k0 + scol]);
    *(s16x8*)(&As[64 + srow][scol]) = *(const s16x8*)(&A[(size_t)(m0 + 64 + srow)*lda + k0 + scol]);
    *(s16x8*)(&Bs[srow][scol])      = *(const s16x8*)(&B[(size_t)(n0 + srow)*ldb + k0 + scol]);
    *(s16x8*)(&Bs[64 + srow][scol]) = *(const s16x8*)(&B[(size_t)(n0 + 64 + srow)*ldb + k0 + scol]);
    __syncthreads();
    s16x8 af[4], bf[4];
    #pragma unroll
    for (int i = 0; i < 4; i++) af[i] = *(const s16x8*)(&As[wm + i*16 + fr][fk]);
    #pragma unroll
    for (int i = 0; i < 4; i++) bf[i] = *(const s16x8*)(&Bs[wn + i*16 + fr][fk]);
    #pragma unroll
    for (int mi = 0; mi < 4; mi++)
      #pragma unroll
      for (int ni = 0; ni < 4; ni++)
        acc[mi][ni] = __builtin_amdgcn_mfma_f32_16x16x32_bf16(af[mi], bf[ni], acc[mi][ni], 0, 0, 0);
    __syncthreads();
  }
  int cr = (lane >> 4) * 4, cc = lane & 15;
  #pragma unroll
  for (int mi = 0; mi < 4; mi++)
    #pragma unroll
    for (int ni = 0; ni < 4; ni++) {
      int rowb = m0 + wm + mi*16 + cr, col = n0 + wn + ni*16 + cc;
      #pragma unroll
      for (int r = 0; r < 4; r++) {
        float v = acc[mi][ni][r];
        if (clampFinite && !isfinite(v)) v = 0.f;
        C[(size_t)(rowb + r)*N + col] = v;
      }
    }
}

// ---------------- depthwise causal conv + silu ----------------
__global__ __launch_bounds__(256) void conv_silu_kernel(
    const float* __restrict__ xsres, const float* __restrict__ cw,
    const float* __restrict__ cb, float* __restrict__ u)
{
  int idx = blockIdx.x*256 + threadIdx.x;
  int d = (idx & 127) * 4;
  int row = idx >> 7;                 // b*SEQ + l
  int l = row & (SEQ - 1);
  float w[4][4];
  #pragma unroll
  for (int c = 0; c < 4; c++) *(float4*)w[c] = *(const float4*)&cw[(d + c)*4];
  float4 acc = *(const float4*)&cb[d];
  #pragma unroll
  for (int k = 0; k < 4; k++) {
    int li = l - 3 + k;
    if (li >= 0) {
      float4 v = *(const float4*)&xsres[(size_t)(row - 3 + k)*1024 + d];
      acc.x += v.x*w[0][k]; acc.y += v.y*w[1][k];
      acc.z += v.z*w[2][k]; acc.w += v.w*w[3][k];
    }
  }
  float4 o;
  o.x = acc.x/(1.f+expf(-acc.x)); o.y = acc.y/(1.f+expf(-acc.y));
  o.z = acc.z/(1.f+expf(-acc.z)); o.w = acc.w/(1.f+expf(-acc.w));
  *(float4*)&u[(size_t)row*D_MODEL + d] = o;
}

// ---------------- x_proj + dt_proj + softplus fused ----------------
__global__ __launch_bounds__(256) void xproj_kernel(
    const float* __restrict__ u, const float* __restrict__ xpw,
    const float* __restrict__ dtw, const float* __restrict__ dtb,
    float* __restrict__ delta, float* __restrict__ Bv, float* __restrict__ Cv)
{
  int row = blockIdx.x;
  int t = threadIdx.x;
  __shared__ float us[D_MODEL];
  __shared__ float xd[64];
  *(float2*)&us[t*2] = *(const float2*)&u[(size_t)row*D_MODEL + t*2];
  __syncthreads();
  int o = t >> 2, sub = t & 3;
  {
    const float* w = &xpw[(size_t)o*D_MODEL + sub*128];
    const float* uu = &us[sub*128];
    float s = 0.f;
    #pragma unroll 8
    for (int k = 0; k < 128; k += 4) {
      float4 wv = *(const float4*)&w[k];
      s += wv.x*uu[k] + wv.y*uu[k+1] + wv.z*uu[k+2] + wv.w*uu[k+3];
    }
    s += __shfl_down(s, 2); s += __shfl_down(s, 1);
    if (sub == 0) xd[o] = s;
  }
  __syncthreads();
  #pragma unroll
  for (int rep = 0; rep < 2; rep++) {
    int d = t + rep*256;
    float s2 = dtb[d];
    const float* w2 = &dtw[(size_t)d*DT_RANK];
    #pragma unroll
    for (int k = 0; k < DT_RANK; k += 4) {
      float4 wv = *(const float4*)&w2[k];
      s2 += wv.x*xd[k] + wv.y*xd[k+1] + wv.z*xd[k+2] + wv.w*xd[k+3];
    }
    s2 = (s2 > 20.f) ? s2 : log1pf(expf(s2));  // softplus
    delta[(size_t)row*D_MODEL + d] = s2;
  }
  if (t < D_STATE)            Bv[(size_t)row*D_STATE + t] = xd[DT_RANK + t];
  else if (t < 2*D_STATE)     Cv[(size_t)row*D_STATE + (t - D_STATE)] = xd[DT_RANK + t];
}

// ---------------- transpose delta [b][l][d] f32 -> [b][d][l] bf16 ----------------
__global__ __launch_bounds__(256) void transpose_bf16_kernel(
    const float* __restrict__ delta, u16* __restrict__ deltaT)
{
  __shared__ u16 tile[32][33];
  int l0 = blockIdx.x*32, d0 = blockIdx.y*32, b = blockIdx.z;
  int tx = threadIdx.x & 31, ty = threadIdx.x >> 5;
  #pragma unroll
  for (int r = ty; r < 32; r += 8)
    tile[r][tx] = f2bf(delta[((size_t)b*SEQ + l0 + r)*D_MODEL + d0 + tx]);
  __syncthreads();
  #pragma unroll
  for (int r = ty; r < 32; r += 8)
    deltaT[((size_t)b*D_MODEL + d0 + r)*SEQ + l0 + tx] = tile[tx][r];
}

// ---------------- scan phase A: per-chunk local state + sum(dp) ----------------
__global__ __launch_bounds__(256) void scanA_kernel(
    const float* __restrict__ dp, const float* __restrict__ u,
    const float* __restrict__ Bv, const float* __restrict__ A_log,
    float* __restrict__ slocal, float* __restrict__ sumdp_out)
{
  int d = blockIdx.x*256 + threadIdx.x;
  int c = blockIdx.y, b = blockIdx.z;
  __shared__ float Bs[64][D_STATE];
  int t = threadIdx.x;
  size_t lbase = (size_t)b*SEQ + c*64;
  #pragma unroll
  for (int i = 0; i < 4; i++) {
    int idx = t + i*256;
    Bs[idx >> 4][idx & 15] = Bv[(lbase + (idx >> 4))*D_STATE + (idx & 15)];
  }
  float a[D_STATE];
  #pragma unroll
  for (int n = 0; n < D_STATE; n += 4) {
    float4 v = *(const float4*)&A_log[(size_t)d*D_STATE + n];
    a[n] = -expf(v.x); a[n+1] = -expf(v.y); a[n+2] = -expf(v.z); a[n+3] = -expf(v.w);
  }
  __syncthreads();
  float s[D_STATE];
  #pragma unroll
  for (int n = 0; n < D_STATE; n++) s[n] = 0.f;
  float sd = 0.f;
  for (int j = 0; j < 64; j++) {
    size_t r = lbase + j;
    float dpv = dp[r*D_MODEL + d];
    float uv  = u[r*D_MODEL + d];
    sd += dpv;
    float dbu = dpv * uv;
    #pragma unroll
    for (int n = 0; n < D_STATE; n++)
      s[n] = __expf(a[n]*dpv)*s[n] + dbu*Bs[j][n];
  }
  size_t obase = ((size_t)b*32 + c)*D_MODEL + d;
  #pragma unroll
  for (int n = 0; n < D_STATE; n += 4)
    *(float4*)&slocal[obase*D_STATE + n] = make_float4(s[n], s[n+1], s[n+2], s[n+3]);
  sumdp_out[obase] = sd;
}

// ---------------- scan phase B: propagate chunk carries ----------------
__global__ __launch_bounds__(256) void scanB_kernel(
    const float* __restrict__ slocal, const float* __restrict__ sumdp,
    const float* __restrict__ A_log, float* __restrict__ sIn)
{
  int g = blockIdx.x*256 + threadIdx.x;   // 32768 = b*8192 + d*16 + n
  int n = g & 15, d = (g >> 4) & (D_MODEL - 1), b = g >> 13;
  float a = -expf(A_log[d*D_STATE + n]);
  float s = 0.f;
  for (int c = 0; c < 32; c++) {
    size_t idx = ((size_t)b*32 + c)*D_MODEL + d;
    sIn[idx*D_STATE + n] = s;
    s = __expf(a * sumdp[idx]) * s + slocal[idx*D_STATE + n];
  }
}

// ---------------- scan phase C: outputs + gating, writes y bf16 ----------------
__global__ __launch_bounds__(256) void scanC_kernel(
    const float* __restrict__ dp, const float* __restrict__ u,
    const float* __restrict__ Bv, const float* __restrict__ Cv,
    const float* __restrict__ A_log, const float* __restrict__ Dp,
    const float* __restrict__ xsres, const float* __restrict__ sIn,
    u16* __restrict__ yout)
{
  int d = blockIdx.x*256 + threadIdx.x;
  int c = blockIdx.y, b = blockIdx.z;
  __shared__ float Bs[64][D_STATE];
  __shared__ float Cs[64][D_STATE];
  int t = threadIdx.x;
  size_t lbase = (size_t)b*SEQ + c*64;
  #pragma unroll
  for (int i = 0; i < 4; i++) {
    int idx = t + i*256;
    Bs[idx >> 4][idx & 15] = Bv[(lbase + (idx >> 4))*D_STATE + (idx & 15)];
    Cs[idx >> 4][idx & 15] = Cv[(lbase + (idx >> 4))*D_STATE + (idx & 15)];
  }
  float a[D_STATE];
  #pragma unroll
  for (int n = 0; n < D_STATE; n += 4) {
    float4 v = *(const float4*)&A_log[(size_t)d*D_STATE + n];
    a[n] = -expf(v.x); a[n+1] = -expf(v.y); a[n+2] = -expf(v.z); a[n+3] = -expf(v.w);
  }
  float s[D_STATE];
  size_t ibase = (((size_t)b*32 + c)*D_MODEL + d)*D_STATE;
  #pragma unroll
  for (int n = 0; n < D_STATE; n += 4) {
    float4 v = *(const float4*)&sIn[ibase + n];
    s[n] = v.x; s[n+1] = v.y; s[n+2] = v.z; s[n+3] = v.w;
  }
  float dparam = Dp[d];
  __syncthreads();
  for (int j = 0; j < 64; j++) {
    size_t r = lbase + j;
    float dpv = dp[r*D_MODEL + d];
    float uv  = u[r*D_MODEL + d];
    float dbu = dpv * uv;
    float y = 0.f;
    #pragma unroll
    for (int n = 0; n < D_STATE; n++) {
      s[n] = __expf(a[n]*dpv)*s[n] + dbu*Bs[j][n];
      y += s[n]*Cs[j][n];
    }
    y += uv * dparam;
    float rr = xsres[r*1024 + D_MODEL + d];
    y *= rr/(1.f + __expf(-rr));       // silu(res)
    yout[r*D_MODEL + d] = f2bf(y);
  }
}

extern "C" void kernel_launch(void* const* d_in, const int* in_sizes, int n_in,
                              void* d_out, int out_size, void* d_ws, size_t ws_size,
                              hipStream_t stream)
{
  const float* atoms  = (const float*)d_in[0];
  const float* dis    = (const float*)d_in[1];
  const float* gpt    = (const float*)d_in[2];
  const float* fg     = (const float*)d_in[3];
  const float* inw    = (const float*)d_in[4];
  const float* convw  = (const float*)d_in[5];
  const float* convb  = (const float*)d_in[6];
  const float* xpw    = (const float*)d_in[7];
  const float* dtw    = (const float*)d_in[8];
  const float* dtb    = (const float*)d_in[9];
  const float* A_log  = (const float*)d_in[10];
  const float* Dparam = (const float*)d_in[11];
  const float* outw   = (const float*)d_in[12];
  const float* fw1    = (const float*)d_in[13];
  const float* fb1    = (const float*)d_in[14];
  const float* fw2    = (const float*)d_in[15];
  const float* fb2    = (const float*)d_in[16];

  char* ws = (char*)d_ws;
  size_t off = 0;
  auto alloc = [&](size_t bytes) { char* p = ws + off; off += (bytes + 255) & ~255ull; return p; };
  float* gb     = (float*)alloc((size_t)NBATCH*1024*4);
  u16*   xbf    = (u16*)  alloc((size_t)8192*512*2);          // later reused as y bf16
  u16*   inwbf  = (u16*)  alloc((size_t)1024*512*2);
  u16*   outwbf = (u16*)  alloc((size_t)512*512*2);
  u16*   disbf  = (u16*)  alloc((size_t)NBATCH*2048*2048*2);
  float* xsres  = (float*)alloc((size_t)8192*1024*4);
  float* delta  = (float*)alloc((size_t)8192*512*4);          // reused as dp
  float* ubuf   = (float*)alloc((size_t)8192*512*4);
  float* Bv     = (float*)alloc((size_t)8192*16*4);
  float* Cv     = (float*)alloc((size_t)8192*16*4);
  u16*   deltaT = (u16*)  alloc((size_t)NBATCH*512*2048*2);
  float* slocal = (float*)alloc((size_t)NBATCH*32*512*16*4);
  float* sumdp  = (float*)alloc((size_t)NBATCH*32*512*4);
  float* sIn    = (float*)alloc((size_t)NBATCH*32*512*16*4);

  film_kernel<<<NBATCH, 512, 0, stream>>>(gpt, fw1, fb1, fw2, fb2, gb);
  xattn_kernel<<<dim3(SEQ, NBATCH), 256, 0, stream>>>(atoms, fg, gb, xbf);
  cvt_bf16_kernel<<<(1024*512/4 + 255)/256, 256, 0, stream>>>(inw, inwbf, 1024*512/4);
  cvt_bf16_kernel<<<(512*512/4 + 255)/256, 256, 0, stream>>>(outw, outwbf, 512*512/4);
  cvt_bf16_kernel<<<(NBATCH*2048*2048/4 + 255)/256, 256, 0, stream>>>(dis, disbf, NBATCH*2048*2048/4);

  // in_proj: [8192,512] @ [1024,512]^T -> xs_res
  gemm_bt_kernel<<<dim3(1024/128, 8192/128, 1), 256, 0, stream>>>(
      xbf, inwbf, xsres, 8192, 1024, 512, 0, 0, 0, 0);
  conv_silu_kernel<<<8192*128/256, 256, 0, stream>>>(xsres, convw, convb, ubuf);
  xproj_kernel<<<8192, 256, 0, stream>>>(ubuf, xpw, dtw, dtb, delta, Bv, Cv);
  transpose_bf16_kernel<<<dim3(SEQ/32, D_MODEL/32, NBATCH), 256, 0, stream>>>(delta, deltaT);

  // delta_p: per-batch [2048,2048] @ [512,2048]^T -> dp (reuses delta)
  float* dp = delta;
  gemm_bt_kernel<<<dim3(512/128, 2048/128, NBATCH), 256, 0, stream>>>(
      disbf, deltaT, dp, 2048, 512, 2048,
      (long long)2048*2048, (long long)512*2048, (long long)2048*512, 0);

  scanA_kernel<<<dim3(2, 32, NBATCH), 256, 0, stream>>>(dp, ubuf, Bv, A_log, slocal, sumdp);
  scanB_kernel<<<32768/256, 256, 0, stream>>>(slocal, sumdp, A_log, sIn);
  u16* ybf = xbf;
  scanC_kernel<<<dim3(2, 32, NBATCH), 256, 0, stream>>>(dp, ubuf, Bv, Cv, A_log, Dparam, xsres, sIn, ybf);

  // out_proj: [8192,512] @ [512,512]^T -> out (with finite clamp)
  gemm_bt_kernel<<<dim3(512/128, 8192/128, 1), 256, 0, stream>>>(
      ybf, outwbf, (float*)d_out, 8192, 512, 512, 0, 0, 0, 1);
}

// Round 2
// 371.224 us; speedup vs baseline: 1.5296x; 1.5296x over previous
//
#include <hip/hip_runtime.h>
#include <stdint.h>

#define D_MODEL 512
#define D_STATE 16
#define DT_RANK 32
#define SEQ 2048
#define NBATCH 4
#define FN 32

typedef unsigned short u16;
using s16x8 = __attribute__((ext_vector_type(8))) short;
using f32x4 = __attribute__((ext_vector_type(4))) float;

typedef __attribute__((address_space(3))) void lds_void;
typedef __attribute__((address_space(1))) const void glb_void;

__device__ __forceinline__ void gload16(const void* g, void* l) {
  __builtin_amdgcn_global_load_lds((glb_void*)g, (lds_void*)l, 16, 0, 0);
}

__device__ inline u16 f2bf(float f) {
  uint32_t u = __float_as_uint(f);
  u += 0x7FFFu + ((u >> 16) & 1u);   // RNE
  return (u16)(u >> 16);
}

// ---------------- FiLM stage 1: h = silu(gpt @ w1^T + b1) ----------------
__global__ __launch_bounds__(256) void film1_kernel(
    const float* __restrict__ gpt, const float* __restrict__ w1,
    const float* __restrict__ b1, float* __restrict__ h)
{
  int b = blockIdx.y, r0 = blockIdx.x*16, t = threadIdx.x;
  __shared__ float g[D_MODEL];
  for (int i = t; i < D_MODEL; i += 256) g[i] = gpt[b*D_MODEL + i];
  __syncthreads();
  int r = r0 + (t >> 4), ln = t & 15;
  const float* wr = &w1[(size_t)r*D_MODEL + ln*32];
  const float* gg = &g[ln*32];
  float s = 0.f;
  #pragma unroll
  for (int k = 0; k < 32; k += 4) {
    float4 w = *(const float4*)&wr[k];
    s += w.x*gg[k] + w.y*gg[k+1] + w.z*gg[k+2] + w.w*gg[k+3];
  }
  s += __shfl_down(s, 8); s += __shfl_down(s, 4);
  s += __shfl_down(s, 2); s += __shfl_down(s, 1);
  if (ln == 0) { float v = s + b1[r]; h[b*D_MODEL + r] = v / (1.f + expf(-v)); }
}

// ---------------- FiLM stage 2: gb = h @ w2^T + b2 (gamma|beta) ----------------
__global__ __launch_bounds__(256) void film2_kernel(
    const float* __restrict__ h, const float* __restrict__ w2,
    const float* __restrict__ b2, float* __restrict__ gb)
{
  int b = blockIdx.y, r0 = blockIdx.x*16, t = threadIdx.x;
  __shared__ float hs[D_MODEL];
  for (int i = t; i < D_MODEL; i += 256) hs[i] = h[b*D_MODEL + i];
  __syncthreads();
  int r = r0 + (t >> 4), ln = t & 15;
  const float* wr = &w2[(size_t)r*D_MODEL + ln*32];
  const float* gg = &hs[ln*32];
  float s = 0.f;
  #pragma unroll
  for (int k = 0; k < 32; k += 4) {
    float4 w = *(const float4*)&wr[k];
    s += w.x*gg[k] + w.y*gg[k+1] + w.z*gg[k+2] + w.w*gg[k+3];
  }
  s += __shfl_down(s, 8); s += __shfl_down(s, 4);
  s += __shfl_down(s, 2); s += __shfl_down(s, 1);
  if (ln == 0) gb[b*1024 + r] = s + b2[r];
}

// ---------------- cross-attn + FiLM, 32 rows/block, fg staged in LDS ----------------
__global__ __launch_bounds__(256) void xattn_kernel(
    const float* __restrict__ atoms, const float* __restrict__ fg,
    const float* __restrict__ gb, u16* __restrict__ xout)
{
  int b = blockIdx.y, l0 = blockIdx.x*32, t = threadIdx.x;
  __shared__ float fgs[FN][516];
  __shared__ float attn_s[32][32];
  {
    const float* src = &fg[(size_t)b*FN*D_MODEL];
    for (int i = t*4; i < FN*D_MODEL; i += 1024) {
      float4 v = *(const float4*)&src[i];
      *(float4*)&fgs[i >> 9][i & 511] = v;
    }
  }
  __syncthreads();
  int f = t & 31, rr = t >> 5;
  for (int pass = 0; pass < 4; pass++) {
    int r = pass*8 + rr;
    const float* arow = &atoms[((size_t)b*SEQ + l0 + r)*D_MODEL];
    float s = 0.f;
    #pragma unroll 8
    for (int k = 0; k < D_MODEL; k += 4) {
      float4 a4 = *(const float4*)&arow[k];
      float4 g4 = *(const float4*)&fgs[f][k];
      s += a4.x*g4.x + a4.y*g4.y + a4.z*g4.z + a4.w*g4.w;
    }
    s *= 0.04419417382415922f;   // 1/sqrt(512)
    float m = s;
    #pragma unroll
    for (int o = 16; o; o >>= 1) m = fmaxf(m, __shfl_xor(m, o));
    float e = __expf(s - m);
    float sum = e;
    #pragma unroll
    for (int o = 16; o; o >>= 1) sum += __shfl_xor(sum, o);
    attn_s[r][f] = e / sum;
  }
  __syncthreads();
  int dq = (t & 127)*4, r2 = t >> 7;
  const float* gbg = &gb[(size_t)b*1024];
  float4 gm = *(const float4*)&gbg[dq];
  float4 bt = *(const float4*)&gbg[D_MODEL + dq];
  for (int pass = 0; pass < 16; pass++) {
    int r = pass*2 + r2;
    size_t row = (size_t)b*SEQ + l0 + r;
    float4 acc = *(const float4*)&atoms[row*D_MODEL + dq];
    #pragma unroll 8
    for (int f2 = 0; f2 < FN; f2++) {
      float w = attn_s[r][f2];
      float4 g4 = *(const float4*)&fgs[f2][dq];
      acc.x += w*g4.x; acc.y += w*g4.y; acc.z += w*g4.z; acc.w += w*g4.w;
    }
    ushort4 o;
    o.x = f2bf(acc.x*gm.x + bt.x); o.y = f2bf(acc.y*gm.y + bt.y);
    o.z = f2bf(acc.z*gm.z + bt.z); o.w = f2bf(acc.w*gm.w + bt.w);
    *(ushort4*)&xout[row*D_MODEL + dq] = o;
  }
}

// ---------------- f32 -> bf16 convert ----------------
__global__ __launch_bounds__(256) void cvt_bf16_kernel(
    const float* __restrict__ in, u16* __restrict__ out, int n4)
{
  int i = blockIdx.x*256 + threadIdx.x;
  if (i >= n4) return;
  float4 v = *(const float4*)&in[(size_t)i*4];
  ushort4 o; o.x = f2bf(v.x); o.y = f2bf(v.y); o.z = f2bf(v.z); o.w = f2bf(v.w);
  *(ushort4*)&out[(size_t)i*4] = o;
}

// ---------------- W_eff[d][k] = sum_r dtw[d][r]*xpw[r][k], bf16 ----------------
__global__ __launch_bounds__(256) void build_weff_kernel(
    const float* __restrict__ dtw, const float* __restrict__ xpw, u16* __restrict__ weff)
{
  int d = blockIdx.x, t = threadIdx.x;
  __shared__ float dr[DT_RANK];
  if (t < DT_RANK) dr[t] = dtw[d*DT_RANK + t];
  __syncthreads();
  for (int k = t; k < D_MODEL; k += 256) {
    float s = 0.f;
    #pragma unroll
    for (int r = 0; r < DT_RANK; r++) s += dr[r] * xpw[r*D_MODEL + k];
    weff[d*D_MODEL + k] = f2bf(s);
  }
}

// ---------------- bf16 GEMM: C[M][N] = A[M][K] @ Bt[N][K]^T, fp32 out ----------------
__global__ __launch_bounds__(256) void gemm_bt_kernel(
    const u16* __restrict__ Ag, const u16* __restrict__ Bg, float* __restrict__ Cg,
    int M, int N, int K, long long azs, long long bzs, long long czs, int clampFinite)
{
  const u16* A = Ag + (size_t)blockIdx.z * azs;
  const u16* B = Bg + (size_t)blockIdx.z * bzs;
  float* C = Cg + (size_t)blockIdx.z * czs;
  int m0 = blockIdx.y * 128, n0 = blockIdx.x * 128;
  __shared__ u16 As[128][32];
  __shared__ u16 Bs[128][32];
  int tid = threadIdx.x, lane = tid & 63, wave = tid >> 6;
  int wm = (wave >> 1) * 64, wn = (wave & 1) * 64;
  int fr = lane & 15, fk = (lane >> 4) * 8;
  int srow = tid >> 2, scol = (tid & 3) * 8;
  f32x4 acc[4][4] = {};
  const size_t lda = K, ldb = K;
  for (int k0 = 0; k0 < K; k0 += 32) {
    gload16(&A[(size_t)(m0 + srow)*lda + k0 + scol],      &As[srow][scol]);
    gload16(&A[(size_t)(m0 + 64 + srow)*lda + k0 + scol], &As[64 + srow][scol]);
    gload16(&B[(size_t)(n0 + srow)*ldb + k0 + scol],      &Bs[srow][scol]);
    gload16(&B[(size_t)(n0 + 64 + srow)*ldb + k0 + scol], &Bs[64 + srow][scol]);
    __syncthreads();
    s16x8 af[4], bf[4];
    #pragma unroll
    for (int i = 0; i < 4; i++) af[i] = *(const s16x8*)(&As[wm + i*16 + fr][fk]);
    #pragma unroll
    for (int i = 0; i < 4; i++) bf[i] = *(const s16x8*)(&Bs[wn + i*16 + fr][fk]);
    #pragma unroll
    for (int mi = 0; mi < 4; mi++)
      #pragma unroll
      for (int ni = 0; ni < 4; ni++)
        acc[mi][ni] = __builtin_amdgcn_mfma_f32_16x16x32_bf16(af[mi], bf[ni], acc[mi][ni], 0, 0, 0);
    __syncthreads();
  }
  int cr = (lane >> 4) * 4, cc = lane & 15;
  #pragma unroll
  for (int mi = 0; mi < 4; mi++)
    #pragma unroll
    for (int ni = 0; ni < 4; ni++) {
      int rowb = m0 + wm + mi*16 + cr, col = n0 + wn + ni*16 + cc;
      #pragma unroll
      for (int r = 0; r < 4; r++) {
        float v = acc[mi][ni][r];
        if (clampFinite && !isfinite(v)) v = 0.f;
        C[(size_t)(rowb + r)*N + col] = v;
      }
    }
}

// ---------------- depthwise causal conv + silu (writes u fp32 + bf16) ----------------
__global__ __launch_bounds__(256) void conv_silu_kernel(
    const float* __restrict__ xsres, const float* __restrict__ cw,
    const float* __restrict__ cb, float* __restrict__ u, u16* __restrict__ ubf)
{
  int idx = blockIdx.x*256 + threadIdx.x;
  int d = (idx & 127) * 4;
  int row = idx >> 7;                 // b*SEQ + l
  int l = row & (SEQ - 1);
  float w[4][4];
  #pragma unroll
  for (int c = 0; c < 4; c++) *(float4*)w[c] = *(const float4*)&cw[(d + c)*4];
  float4 acc = *(const float4*)&cb[d];
  #pragma unroll
  for (int k = 0; k < 4; k++) {
    int li = l - 3 + k;
    if (li >= 0) {
      float4 v = *(const float4*)&xsres[(size_t)(row - 3 + k)*1024 + d];
      acc.x += v.x*w[0][k]; acc.y += v.y*w[1][k];
      acc.z += v.z*w[2][k]; acc.w += v.w*w[3][k];
    }
  }
  float4 o;
  o.x = acc.x/(1.f+expf(-acc.x)); o.y = acc.y/(1.f+expf(-acc.y));
  o.z = acc.z/(1.f+expf(-acc.z)); o.w = acc.w/(1.f+expf(-acc.w));
  *(float4*)&u[(size_t)row*D_MODEL + d] = o;
  ushort4 ob;
  ob.x = f2bf(o.x); ob.y = f2bf(o.y); ob.z = f2bf(o.z); ob.w = f2bf(o.w);
  *(ushort4*)&ubf[(size_t)row*D_MODEL + d] = ob;
}

// ---------------- B/C projection, fp32, u staged in LDS ----------------
__global__ __launch_bounds__(256) void bc_kernel(
    const float* __restrict__ u, const float* __restrict__ xpw,
    float* __restrict__ Bv, float* __restrict__ Cv)
{
  int row0 = blockIdx.x * 16, t = threadIdx.x;
  __shared__ float us[16][516];
  for (int i = t*4; i < 16*D_MODEL; i += 1024) {
    float4 v = *(const float4*)&u[(size_t)row0*D_MODEL + i];
    *(float4*)&us[i >> 9][i & 511] = v;
  }
  __syncthreads();
  int r = t >> 4, n = t & 15;
  const float* wB = &xpw[(size_t)(DT_RANK + n)*D_MODEL];
  const float* wC = &xpw[(size_t)(DT_RANK + 16 + n)*D_MODEL];
  const float* ur = us[r];
  float sB = 0.f, sC = 0.f;
  #pragma unroll 8
  for (int k = 0; k < D_MODEL; k += 4) {
    float4 uv = *(const float4*)&ur[k];
    float4 b4 = *(const float4*)&wB[k];
    float4 c4 = *(const float4*)&wC[k];
    sB += uv.x*b4.x + uv.y*b4.y + uv.z*b4.z + uv.w*b4.w;
    sC += uv.x*c4.x + uv.y*c4.y + uv.z*c4.z + uv.w*c4.w;
  }
  Bv[(size_t)(row0 + r)*D_STATE + n] = sB;
  Cv[(size_t)(row0 + r)*D_STATE + n] = sC;
}

// ---------------- bias + softplus + transpose -> deltaT bf16 ----------------
__global__ __launch_bounds__(256) void softplus_T_kernel(
    const float* __restrict__ dpre, const float* __restrict__ dtb, u16* __restrict__ deltaT)
{
  __shared__ u16 tile[32][33];
  int l0 = blockIdx.x*32, d0 = blockIdx.y*32, b = blockIdx.z;
  int tx = threadIdx.x & 31, ty = threadIdx.x >> 5;
  #pragma unroll
  for (int r = ty; r < 32; r += 8) {
    float v = dpre[((size_t)b*SEQ + l0 + r)*D_MODEL + d0 + tx] + dtb[d0 + tx];
    v = (v > 20.f) ? v : log1pf(expf(v));
    tile[r][tx] = f2bf(v);
  }
  __syncthreads();
  #pragma unroll
  for (int r = ty; r < 32; r += 8)
    deltaT[((size_t)b*D_MODEL + d0 + r)*SEQ + l0 + tx] = tile[tx][r];
}

// ---------------- scan phase A: per-chunk local state + sum(dp) ----------------
__global__ __launch_bounds__(256) void scanA_kernel(
    const float* __restrict__ dp, const float* __restrict__ u,
    const float* __restrict__ Bv, const float* __restrict__ A_log,
    float* __restrict__ slocal, float* __restrict__ sumdp_out)
{
  int d = blockIdx.x*256 + threadIdx.x;
  int c = blockIdx.y, b = blockIdx.z;
  __shared__ float Bs[64][D_STATE];
  int t = threadIdx.x;
  size_t lbase = (size_t)b*SEQ + c*64;
  #pragma unroll
  for (int i = 0; i < 4; i++) {
    int idx = t + i*256;
    Bs[idx >> 4][idx & 15] = Bv[(lbase + (idx >> 4))*D_STATE + (idx & 15)];
  }
  float a[D_STATE];
  #pragma unroll
  for (int n = 0; n < D_STATE; n += 4) {
    float4 v = *(const float4*)&A_log[(size_t)d*D_STATE + n];
    a[n] = -expf(v.x); a[n+1] = -expf(v.y); a[n+2] = -expf(v.z); a[n+3] = -expf(v.w);
  }
  __syncthreads();
  float s[D_STATE];
  #pragma unroll
  for (int n = 0; n < D_STATE; n++) s[n] = 0.f;
  float sd = 0.f;
  for (int j = 0; j < 64; j++) {
    size_t r = lbase + j;
    float dpv = dp[r*D_MODEL + d];
    float uv  = u[r*D_MODEL + d];
    sd += dpv;
    float dbu = dpv * uv;
    #pragma unroll
    for (int n = 0; n < D_STATE; n++)
      s[n] = __expf(a[n]*dpv)*s[n] + dbu*Bs[j][n];
  }
  size_t obase = ((size_t)b*32 + c)*D_MODEL + d;
  #pragma unroll
  for (int n = 0; n < D_STATE; n += 4)
    *(float4*)&slocal[obase*D_STATE + n] = make_float4(s[n], s[n+1], s[n+2], s[n+3]);
  sumdp_out[obase] = sd;
}

// ---------------- scan phase B: propagate chunk carries ----------------
__global__ __launch_bounds__(256) void scanB_kernel(
    const float* __restrict__ slocal, const float* __restrict__ sumdp,
    const float* __restrict__ A_log, float* __restrict__ sIn)
{
  int g = blockIdx.x*256 + threadIdx.x;   // 32768 = b*8192 + d*16 + n
  int n = g & 15, d = (g >> 4) & (D_MODEL - 1), b = g >> 13;
  float a = -expf(A_log[d*D_STATE + n]);
  float s = 0.f;
  for (int c = 0; c < 32; c++) {
    size_t idx = ((size_t)b*32 + c)*D_MODEL + d;
    sIn[idx*D_STATE + n] = s;
    s = __expf(a * sumdp[idx]) * s + slocal[idx*D_STATE + n];
  }
}

// ---------------- scan phase C: outputs + gating, writes y bf16 ----------------
__global__ __launch_bounds__(256) void scanC_kernel(
    const float* __restrict__ dp, const float* __restrict__ u,
    const float* __restrict__ Bv, const float* __restrict__ Cv,
    const float* __restrict__ A_log, const float* __restrict__ Dp,
    const float* __restrict__ xsres, const float* __restrict__ sIn,
    u16* __restrict__ yout)
{
  int d = blockIdx.x*256 + threadIdx.x;
  int c = blockIdx.y, b = blockIdx.z;
  __shared__ float Bs[64][D_STATE];
  __shared__ float Cs[64][D_STATE];
  int t = threadIdx.x;
  size_t lbase = (size_t)b*SEQ + c*64;
  #pragma unroll
  for (int i = 0; i < 4; i++) {
    int idx = t + i*256;
    Bs[idx >> 4][idx & 15] = Bv[(lbase + (idx >> 4))*D_STATE + (idx & 15)];
    Cs[idx >> 4][idx & 15] = Cv[(lbase + (idx >> 4))*D_STATE + (idx & 15)];
  }
  float a[D_STATE];
  #pragma unroll
  for (int n = 0; n < D_STATE; n += 4) {
    float4 v = *(const float4*)&A_log[(size_t)d*D_STATE + n];
    a[n] = -expf(v.x); a[n+1] = -expf(v.y); a[n+2] = -expf(v.z); a[n+3] = -expf(v.w);
  }
  float s[D_STATE];
  size_t ibase = (((size_t)b*32 + c)*D_MODEL + d)*D_STATE;
  #pragma unroll
  for (int n = 0; n < D_STATE; n += 4) {
    float4 v = *(const float4*)&sIn[ibase + n];
    s[n] = v.x; s[n+1] = v.y; s[n+2] = v.z; s[n+3] = v.w;
  }
  float dparam = Dp[d];
  __syncthreads();
  for (int j = 0; j < 64; j++) {
    size_t r = lbase + j;
    float dpv = dp[r*D_MODEL + d];
    float uv  = u[r*D_MODEL + d];
    float dbu = dpv * uv;
    float y = 0.f;
    #pragma unroll
    for (int n = 0; n < D_STATE; n++) {
      s[n] = __expf(a[n]*dpv)*s[n] + dbu*Bs[j][n];
      y += s[n]*Cs[j][n];
    }
    y += uv * dparam;
    float rr = xsres[r*1024 + D_MODEL + d];
    y *= rr/(1.f + __expf(-rr));       // silu(res)
    yout[r*D_MODEL + d] = f2bf(y);
  }
}

extern "C" void kernel_launch(void* const* d_in, const int* in_sizes, int n_in,
                              void* d_out, int out_size, void* d_ws, size_t ws_size,
                              hipStream_t stream)
{
  const float* atoms  = (const float*)d_in[0];
  const float* dis    = (const float*)d_in[1];
  const float* gpt    = (const float*)d_in[2];
  const float* fg     = (const float*)d_in[3];
  const float* inw    = (const float*)d_in[4];
  const float* convw  = (const float*)d_in[5];
  const float* convb  = (const float*)d_in[6];
  const float* xpw    = (const float*)d_in[7];
  const float* dtw    = (const float*)d_in[8];
  const float* dtb    = (const float*)d_in[9];
  const float* A_log  = (const float*)d_in[10];
  const float* Dparam = (const float*)d_in[11];
  const float* outw   = (const float*)d_in[12];
  const float* fw1    = (const float*)d_in[13];
  const float* fb1    = (const float*)d_in[14];
  const float* fw2    = (const float*)d_in[15];
  const float* fb2    = (const float*)d_in[16];

  char* ws = (char*)d_ws;
  size_t off = 0;
  auto alloc = [&](size_t bytes) { char* p = ws + off; off += (bytes + 255) & ~255ull; return p; };
  float* gb     = (float*)alloc((size_t)NBATCH*1024*4);
  float* hbuf   = (float*)alloc((size_t)NBATCH*512*4);
  u16*   xbf    = (u16*)  alloc((size_t)8192*512*2);          // later reused as y bf16
  u16*   inwbf  = (u16*)  alloc((size_t)1024*512*2);
  u16*   outwbf = (u16*)  alloc((size_t)512*512*2);
  u16*   weff   = (u16*)  alloc((size_t)512*512*2);
  u16*   disbf  = (u16*)  alloc((size_t)NBATCH*2048*2048*2);
  float* xsres  = (float*)alloc((size_t)8192*1024*4);
  float* dpre   = (float*)alloc((size_t)8192*512*4);          // reused as dp
  float* ubuf   = (float*)alloc((size_t)8192*512*4);
  u16*   ubf    = (u16*)  alloc((size_t)8192*512*2);
  float* Bv     = (float*)alloc((size_t)8192*16*4);
  float* Cv     = (float*)alloc((size_t)8192*16*4);
  u16*   deltaT = (u16*)  alloc((size_t)NBATCH*512*2048*2);
  float* slocal = (float*)alloc((size_t)NBATCH*32*512*16*4);
  float* sumdp  = (float*)alloc((size_t)NBATCH*32*512*4);
  float* sIn    = (float*)alloc((size_t)NBATCH*32*512*16*4);

  film1_kernel<<<dim3(32, NBATCH), 256, 0, stream>>>(gpt, fw1, fb1, hbuf);
  film2_kernel<<<dim3(64, NBATCH), 256, 0, stream>>>(hbuf, fw2, fb2, gb);
  xattn_kernel<<<dim3(SEQ/32, NBATCH), 256, 0, stream>>>(atoms, fg, gb, xbf);

  cvt_bf16_kernel<<<(1024*512/4)/256, 256, 0, stream>>>(inw, inwbf, 1024*512/4);
  cvt_bf16_kernel<<<(512*512/4)/256, 256, 0, stream>>>(outw, outwbf, 512*512/4);
  cvt_bf16_kernel<<<(NBATCH*2048*2048/4)/256, 256, 0, stream>>>(dis, disbf, NBATCH*2048*2048/4);
  build_weff_kernel<<<512, 256, 0, stream>>>(dtw, xpw, weff);

  // in_proj: [8192,512] @ [1024,512]^T -> xs_res
  gemm_bt_kernel<<<dim3(1024/128, 8192/128, 1), 256, 0, stream>>>(
      xbf, inwbf, xsres, 8192, 1024, 512, 0, 0, 0, 0);
  conv_silu_kernel<<<8192*128/256, 256, 0, stream>>>(xsres, convw, convb, ubuf, ubf);

  // delta_pre: [8192,512] @ [512,512]^T (W_eff) -> dpre
  gemm_bt_kernel<<<dim3(512/128, 8192/128, 1), 256, 0, stream>>>(
      ubf, weff, dpre, 8192, 512, 512, 0, 0, 0, 0);
  softplus_T_kernel<<<dim3(SEQ/32, D_MODEL/32, NBATCH), 256, 0, stream>>>(dpre, dtb, deltaT);
  bc_kernel<<<8192/16, 256, 0, stream>>>(ubuf, xpw, Bv, Cv);

  // delta_p: per-batch [2048,2048] @ [512,2048]^T -> dp (reuses dpre)
  float* dp = dpre;
  gemm_bt_kernel<<<dim3(512/128, 2048/128, NBATCH), 256, 0, stream>>>(
      disbf, deltaT, dp, 2048, 512, 2048,
      (long long)2048*2048, (long long)512*2048, (long long)2048*512, 0);

  scanA_kernel<<<dim3(2, 32, NBATCH), 256, 0, stream>>>(dp, ubuf, Bv, A_log, slocal, sumdp);
  scanB_kernel<<<32768/256, 256, 0, stream>>>(slocal, sumdp, A_log, sIn);
  u16* ybf = xbf;
  scanC_kernel<<<dim3(2, 32, NBATCH), 256, 0, stream>>>(dp, ubuf, Bv, Cv, A_log, Dparam, xsres, sIn, ybf);

  // out_proj: [8192,512] @ [512,512]^T -> out (with finite clamp)
  gemm_bt_kernel<<<dim3(512/128, 8192/128, 1), 256, 0, stream>>>(
      ybf, outwbf, (float*)d_out, 8192, 512, 512, 0, 0, 0, 1);
}

// Round 3
// 324.551 us; speedup vs baseline: 1.7496x; 1.1438x over previous
//
#include <hip/hip_runtime.h>
#include <stdint.h>

#define D_MODEL 512
#define D_STATE 16
#define DT_RANK 32
#define SEQ 2048
#define NBATCH 4
#define FN 32

typedef unsigned short u16;
using s16x8 = __attribute__((ext_vector_type(8))) short;
using f32x4 = __attribute__((ext_vector_type(4))) float;

typedef __attribute__((address_space(3))) void lds_void;
typedef __attribute__((address_space(1))) const void glb_void;

__device__ __forceinline__ void gload16(const void* g, void* l) {
  __builtin_amdgcn_global_load_lds((glb_void*)g, (lds_void*)l, 16, 0, 0);
}

__device__ inline u16 f2bf(float f) {
  uint32_t u = __float_as_uint(f);
  u += 0x7FFFu + ((u >> 16) & 1u);   // RNE
  return (u16)(u >> 16);
}

// ---------------- FiLM stage 1: h = silu(gpt @ w1^T + b1) ----------------
__global__ __launch_bounds__(256) void film1_kernel(
    const float* __restrict__ gpt, const float* __restrict__ w1,
    const float* __restrict__ b1, float* __restrict__ h)
{
  int b = blockIdx.y, r0 = blockIdx.x*16, t = threadIdx.x;
  __shared__ float g[D_MODEL];
  for (int i = t; i < D_MODEL; i += 256) g[i] = gpt[b*D_MODEL + i];
  __syncthreads();
  int r = r0 + (t >> 4), ln = t & 15;
  const float* wr = &w1[(size_t)r*D_MODEL + ln*32];
  const float* gg = &g[ln*32];
  float s = 0.f;
  #pragma unroll
  for (int k = 0; k < 32; k += 4) {
    float4 w = *(const float4*)&wr[k];
    s += w.x*gg[k] + w.y*gg[k+1] + w.z*gg[k+2] + w.w*gg[k+3];
  }
  s += __shfl_down(s, 8); s += __shfl_down(s, 4);
  s += __shfl_down(s, 2); s += __shfl_down(s, 1);
  if (ln == 0) { float v = s + b1[r]; h[b*D_MODEL + r] = v / (1.f + expf(-v)); }
}

// ---------------- FiLM stage 2: gb = h @ w2^T + b2 (gamma|beta) ----------------
__global__ __launch_bounds__(256) void film2_kernel(
    const float* __restrict__ h, const float* __restrict__ w2,
    const float* __restrict__ b2, float* __restrict__ gb)
{
  int b = blockIdx.y, r0 = blockIdx.x*16, t = threadIdx.x;
  __shared__ float hs[D_MODEL];
  for (int i = t; i < D_MODEL; i += 256) hs[i] = h[b*D_MODEL + i];
  __syncthreads();
  int r = r0 + (t >> 4), ln = t & 15;
  const float* wr = &w2[(size_t)r*D_MODEL + ln*32];
  const float* gg = &hs[ln*32];
  float s = 0.f;
  #pragma unroll
  for (int k = 0; k < 32; k += 4) {
    float4 w = *(const float4*)&wr[k];
    s += w.x*gg[k] + w.y*gg[k+1] + w.z*gg[k+2] + w.w*gg[k+3];
  }
  s += __shfl_down(s, 8); s += __shfl_down(s, 4);
  s += __shfl_down(s, 2); s += __shfl_down(s, 1);
  if (ln == 0) gb[b*1024 + r] = s + b2[r];
}

// ---------------- cross-attn + FiLM, 32 rows/block, fg staged in LDS ----------------
__global__ __launch_bounds__(256) void xattn_kernel(
    const float* __restrict__ atoms, const float* __restrict__ fg,
    const float* __restrict__ gb, u16* __restrict__ xout)
{
  int b = blockIdx.y, l0 = blockIdx.x*32, t = threadIdx.x;
  __shared__ float fgs[FN][516];
  __shared__ float attn_s[32][32];
  {
    const float* src = &fg[(size_t)b*FN*D_MODEL];
    for (int i = t*4; i < FN*D_MODEL; i += 1024) {
      float4 v = *(const float4*)&src[i];
      *(float4*)&fgs[i >> 9][i & 511] = v;
    }
  }
  __syncthreads();
  int f = t & 31, rr = t >> 5;
  for (int pass = 0; pass < 4; pass++) {
    int r = pass*8 + rr;
    const float* arow = &atoms[((size_t)b*SEQ + l0 + r)*D_MODEL];
    float s = 0.f;
    #pragma unroll 8
    for (int k = 0; k < D_MODEL; k += 4) {
      float4 a4 = *(const float4*)&arow[k];
      float4 g4 = *(const float4*)&fgs[f][k];
      s += a4.x*g4.x + a4.y*g4.y + a4.z*g4.z + a4.w*g4.w;
    }
    s *= 0.04419417382415922f;   // 1/sqrt(512)
    float m = s;
    #pragma unroll
    for (int o = 16; o; o >>= 1) m = fmaxf(m, __shfl_xor(m, o));
    float e = __expf(s - m);
    float sum = e;
    #pragma unroll
    for (int o = 16; o; o >>= 1) sum += __shfl_xor(sum, o);
    attn_s[r][f] = e / sum;
  }
  __syncthreads();
  int dq = (t & 127)*4, r2 = t >> 7;
  const float* gbg = &gb[(size_t)b*1024];
  float4 gm = *(const float4*)&gbg[dq];
  float4 bt = *(const float4*)&gbg[D_MODEL + dq];
  for (int pass = 0; pass < 16; pass++) {
    int r = pass*2 + r2;
    size_t row = (size_t)b*SEQ + l0 + r;
    float4 acc = *(const float4*)&atoms[row*D_MODEL + dq];
    #pragma unroll 8
    for (int f2 = 0; f2 < FN; f2++) {
      float w = attn_s[r][f2];
      float4 g4 = *(const float4*)&fgs[f2][dq];
      acc.x += w*g4.x; acc.y += w*g4.y; acc.z += w*g4.z; acc.w += w*g4.w;
    }
    ushort4 o;
    o.x = f2bf(acc.x*gm.x + bt.x); o.y = f2bf(acc.y*gm.y + bt.y);
    o.z = f2bf(acc.z*gm.z + bt.z); o.w = f2bf(acc.w*gm.w + bt.w);
    *(ushort4*)&xout[row*D_MODEL + dq] = o;
  }
}

// ---------------- f32 -> bf16 convert ----------------
__global__ __launch_bounds__(256) void cvt_bf16_kernel(
    const float* __restrict__ in, u16* __restrict__ out, int n4)
{
  int i = blockIdx.x*256 + threadIdx.x;
  if (i >= n4) return;
  float4 v = *(const float4*)&in[(size_t)i*4];
  ushort4 o; o.x = f2bf(v.x); o.y = f2bf(v.y); o.z = f2bf(v.z); o.w = f2bf(v.w);
  *(ushort4*)&out[(size_t)i*4] = o;
}

// ---------------- Wcomb[640][512]: [W_eff | xpw B rows | xpw C rows | 0] bf16 ----------------
__global__ __launch_bounds__(256) void build_wcomb_kernel(
    const float* __restrict__ dtw, const float* __restrict__ xpw, u16* __restrict__ w)
{
  int row = blockIdx.x, t = threadIdx.x;   // 640 blocks
  if (row < D_MODEL) {
    __shared__ float dr[DT_RANK];
    if (t < DT_RANK) dr[t] = dtw[row*DT_RANK + t];
    __syncthreads();
    for (int k = t; k < D_MODEL; k += 256) {
      float s = 0.f;
      #pragma unroll
      for (int r = 0; r < DT_RANK; r++) s += dr[r] * xpw[r*D_MODEL + k];
      w[(size_t)row*D_MODEL + k] = f2bf(s);
    }
  } else if (row < D_MODEL + 32) {
    for (int k = t; k < D_MODEL; k += 256)
      w[(size_t)row*D_MODEL + k] = f2bf(xpw[(size_t)(DT_RANK + row - D_MODEL)*D_MODEL + k]);
  } else {
    for (int k = t; k < D_MODEL; k += 256)
      w[(size_t)row*D_MODEL + k] = 0;
  }
}

// ---------------- bf16 GEMM: C[M][N] = A[M][K] @ Bt[N][K]^T, fp32 out ----------------
__global__ __launch_bounds__(256) void gemm_bt_kernel(
    const u16* __restrict__ Ag, const u16* __restrict__ Bg, float* __restrict__ Cg,
    int M, int N, int K, long long azs, long long bzs, long long czs, int clampFinite)
{
  const u16* A = Ag + (size_t)blockIdx.z * azs;
  const u16* B = Bg + (size_t)blockIdx.z * bzs;
  float* C = Cg + (size_t)blockIdx.z * czs;
  int m0 = blockIdx.y * 128, n0 = blockIdx.x * 128;
  __shared__ u16 As[128][32];
  __shared__ u16 Bs[128][32];
  int tid = threadIdx.x, lane = tid & 63, wave = tid >> 6;
  int wm = (wave >> 1) * 64, wn = (wave & 1) * 64;
  int fr = lane & 15, fk = (lane >> 4) * 8;
  int srow = tid >> 2, scol = (tid & 3) * 8;
  f32x4 acc[4][4] = {};
  const size_t lda = K, ldb = K;
  for (int k0 = 0; k0 < K; k0 += 32) {
    gload16(&A[(size_t)(m0 + srow)*lda + k0 + scol],      &As[srow][scol]);
    gload16(&A[(size_t)(m0 + 64 + srow)*lda + k0 + scol], &As[64 + srow][scol]);
    gload16(&B[(size_t)(n0 + srow)*ldb + k0 + scol],      &Bs[srow][scol]);
    gload16(&B[(size_t)(n0 + 64 + srow)*ldb + k0 + scol], &Bs[64 + srow][scol]);
    __syncthreads();
    s16x8 af[4], bf[4];
    #pragma unroll
    for (int i = 0; i < 4; i++) af[i] = *(const s16x8*)(&As[wm + i*16 + fr][fk]);
    #pragma unroll
    for (int i = 0; i < 4; i++) bf[i] = *(const s16x8*)(&Bs[wn + i*16 + fr][fk]);
    #pragma unroll
    for (int mi = 0; mi < 4; mi++)
      #pragma unroll
      for (int ni = 0; ni < 4; ni++)
        acc[mi][ni] = __builtin_amdgcn_mfma_f32_16x16x32_bf16(af[mi], bf[ni], acc[mi][ni], 0, 0, 0);
    __syncthreads();
  }
  int cr = (lane >> 4) * 4, cc = lane & 15;
  #pragma unroll
  for (int mi = 0; mi < 4; mi++)
    #pragma unroll
    for (int ni = 0; ni < 4; ni++) {
      int rowb = m0 + wm + mi*16 + cr, col = n0 + wn + ni*16 + cc;
      #pragma unroll
      for (int r = 0; r < 4; r++) {
        float v = acc[mi][ni][r];
        if (clampFinite && !isfinite(v)) v = 0.f;
        C[(size_t)(rowb + r)*N + col] = v;
      }
    }
}

// ---------------- fused delta/B/C GEMM: ubf[8192,512] @ Wcomb[640,512]^T ----------------
// epilogue: cols<512 -> softplus(x+dtb) -> deltaT (transposed bf16)
//           cols 512..527 -> Bv fp32 ; cols 528..543 -> Cv fp32
__global__ __launch_bounds__(256) void gemm_delta_kernel(
    const u16* __restrict__ A, const u16* __restrict__ B,
    const float* __restrict__ dtb, u16* __restrict__ deltaT,
    float* __restrict__ Bv, float* __restrict__ Cv)
{
  int m0 = blockIdx.y * 128, n0 = blockIdx.x * 128;
  __shared__ u16 As[128][32];
  __shared__ u16 Bs[128][32];
  int tid = threadIdx.x, lane = tid & 63, wave = tid >> 6;
  int wm = (wave >> 1) * 64, wn = (wave & 1) * 64;
  int fr = lane & 15, fk = (lane >> 4) * 8;
  int srow = tid >> 2, scol = (tid & 3) * 8;
  f32x4 acc[4][4] = {};
  for (int k0 = 0; k0 < D_MODEL; k0 += 32) {
    gload16(&A[(size_t)(m0 + srow)*D_MODEL + k0 + scol],      &As[srow][scol]);
    gload16(&A[(size_t)(m0 + 64 + srow)*D_MODEL + k0 + scol], &As[64 + srow][scol]);
    gload16(&B[(size_t)(n0 + srow)*D_MODEL + k0 + scol],      &Bs[srow][scol]);
    gload16(&B[(size_t)(n0 + 64 + srow)*D_MODEL + k0 + scol], &Bs[64 + srow][scol]);
    __syncthreads();
    s16x8 af[4], bf[4];
    #pragma unroll
    for (int i = 0; i < 4; i++) af[i] = *(const s16x8*)(&As[wm + i*16 + fr][fk]);
    #pragma unroll
    for (int i = 0; i < 4; i++) bf[i] = *(const s16x8*)(&Bs[wn + i*16 + fr][fk]);
    #pragma unroll
    for (int mi = 0; mi < 4; mi++)
      #pragma unroll
      for (int ni = 0; ni < 4; ni++)
        acc[mi][ni] = __builtin_amdgcn_mfma_f32_16x16x32_bf16(af[mi], bf[ni], acc[mi][ni], 0, 0, 0);
    __syncthreads();
  }
  int cr = (lane >> 4) * 4, cc = lane & 15;
  #pragma unroll
  for (int mi = 0; mi < 4; mi++)
    #pragma unroll
    for (int ni = 0; ni < 4; ni++) {
      int rowb = m0 + wm + mi*16 + cr, col = n0 + wn + ni*16 + cc;
      if (col < D_MODEL) {
        float bias = dtb[col];
        #pragma unroll
        for (int r = 0; r < 4; r++) {
          float v = acc[mi][ni][r] + bias;
          v = (v > 20.f) ? v : log1pf(expf(v));
          int gr = rowb + r;
          deltaT[((size_t)(gr >> 11)*D_MODEL + col)*SEQ + (gr & (SEQ-1))] = f2bf(v);
        }
      } else if (col < D_MODEL + 16) {
        #pragma unroll
        for (int r = 0; r < 4; r++)
          Bv[(size_t)(rowb + r)*D_STATE + (col - D_MODEL)] = acc[mi][ni][r];
      } else if (col < D_MODEL + 32) {
        #pragma unroll
        for (int r = 0; r < 4; r++)
          Cv[(size_t)(rowb + r)*D_STATE + (col - D_MODEL - 16)] = acc[mi][ni][r];
      }
    }
}

// ---------------- depthwise causal conv + silu (writes u fp32 + bf16) ----------------
__global__ __launch_bounds__(256) void conv_silu_kernel(
    const float* __restrict__ xsres, const float* __restrict__ cw,
    const float* __restrict__ cb, float* __restrict__ u, u16* __restrict__ ubf)
{
  int idx = blockIdx.x*256 + threadIdx.x;
  int d = (idx & 127) * 4;
  int row = idx >> 7;                 // b*SEQ + l
  int l = row & (SEQ - 1);
  float w[4][4];
  #pragma unroll
  for (int c = 0; c < 4; c++) *(float4*)w[c] = *(const float4*)&cw[(d + c)*4];
  float4 acc = *(const float4*)&cb[d];
  #pragma unroll
  for (int k = 0; k < 4; k++) {
    int li = l - 3 + k;
    if (li >= 0) {
      float4 v = *(const float4*)&xsres[(size_t)(row - 3 + k)*1024 + d];
      acc.x += v.x*w[0][k]; acc.y += v.y*w[1][k];
      acc.z += v.z*w[2][k]; acc.w += v.w*w[3][k];
    }
  }
  float4 o;
  o.x = acc.x/(1.f+expf(-acc.x)); o.y = acc.y/(1.f+expf(-acc.y));
  o.z = acc.z/(1.f+expf(-acc.z)); o.w = acc.w/(1.f+expf(-acc.w));
  *(float4*)&u[(size_t)row*D_MODEL + d] = o;
  ushort4 ob;
  ob.x = f2bf(o.x); ob.y = f2bf(o.y); ob.z = f2bf(o.z); ob.w = f2bf(o.w);
  *(ushort4*)&ubf[(size_t)row*D_MODEL + d] = ob;
}

// ---------------- scan phase A: per-chunk local state + sum(dp) ----------------
__global__ __launch_bounds__(256) void scanA_kernel(
    const float* __restrict__ dp, const float* __restrict__ u,
    const float* __restrict__ Bv, const float* __restrict__ A_log,
    float* __restrict__ slocal, float* __restrict__ sumdp_out)
{
  int d = blockIdx.x*256 + threadIdx.x;
  int c = blockIdx.y, b = blockIdx.z;
  __shared__ float Bs[64][D_STATE];
  int t = threadIdx.x;
  size_t lbase = (size_t)b*SEQ + c*64;
  #pragma unroll
  for (int i = 0; i < 4; i++) {
    int idx = t + i*256;
    Bs[idx >> 4][idx & 15] = Bv[(lbase + (idx >> 4))*D_STATE + (idx & 15)];
  }
  float a[D_STATE];
  #pragma unroll
  for (int n = 0; n < D_STATE; n += 4) {
    float4 v = *(const float4*)&A_log[(size_t)d*D_STATE + n];
    a[n] = -expf(v.x); a[n+1] = -expf(v.y); a[n+2] = -expf(v.z); a[n+3] = -expf(v.w);
  }
  __syncthreads();
  float s[D_STATE];
  #pragma unroll
  for (int n = 0; n < D_STATE; n++) s[n] = 0.f;
  float sd = 0.f;
  for (int j = 0; j < 64; j++) {
    size_t r = lbase + j;
    float dpv = dp[r*D_MODEL + d];
    float uv  = u[r*D_MODEL + d];
    sd += dpv;
    float dbu = dpv * uv;
    #pragma unroll
    for (int n = 0; n < D_STATE; n++)
      s[n] = __expf(a[n]*dpv)*s[n] + dbu*Bs[j][n];
  }
  size_t obase = ((size_t)b*32 + c)*D_MODEL + d;
  #pragma unroll
  for (int n = 0; n < D_STATE; n += 4)
    *(float4*)&slocal[obase*D_STATE + n] = make_float4(s[n], s[n+1], s[n+2], s[n+3]);
  sumdp_out[obase] = sd;
}

// ---------------- scan phase B: propagate chunk carries ----------------
__global__ __launch_bounds__(256) void scanB_kernel(
    const float* __restrict__ slocal, const float* __restrict__ sumdp,
    const float* __restrict__ A_log, float* __restrict__ sIn)
{
  int g = blockIdx.x*256 + threadIdx.x;   // 32768 = b*8192 + d*16 + n
  int n = g & 15, d = (g >> 4) & (D_MODEL - 1), b = g >> 13;
  float a = -expf(A_log[d*D_STATE + n]);
  float s = 0.f;
  for (int c = 0; c < 32; c++) {
    size_t idx = ((size_t)b*32 + c)*D_MODEL + d;
    sIn[idx*D_STATE + n] = s;
    s = __expf(a * sumdp[idx]) * s + slocal[idx*D_STATE + n];
  }
}

// ---------------- scan phase C: outputs + gating, writes y bf16 ----------------
__global__ __launch_bounds__(256) void scanC_kernel(
    const float* __restrict__ dp, const float* __restrict__ u,
    const float* __restrict__ Bv, const float* __restrict__ Cv,
    const float* __restrict__ A_log, const float* __restrict__ Dp,
    const float* __restrict__ xsres, const float* __restrict__ sIn,
    u16* __restrict__ yout)
{
  int d = blockIdx.x*256 + threadIdx.x;
  int c = blockIdx.y, b = blockIdx.z;
  __shared__ float Bs[64][D_STATE];
  __shared__ float Cs[64][D_STATE];
  int t = threadIdx.x;
  size_t lbase = (size_t)b*SEQ + c*64;
  #pragma unroll
  for (int i = 0; i < 4; i++) {
    int idx = t + i*256;
    Bs[idx >> 4][idx & 15] = Bv[(lbase + (idx >> 4))*D_STATE + (idx & 15)];
    Cs[idx >> 4][idx & 15] = Cv[(lbase + (idx >> 4))*D_STATE + (idx & 15)];
  }
  float a[D_STATE];
  #pragma unroll
  for (int n = 0; n < D_STATE; n += 4) {
    float4 v = *(const float4*)&A_log[(size_t)d*D_STATE + n];
    a[n] = -expf(v.x); a[n+1] = -expf(v.y); a[n+2] = -expf(v.z); a[n+3] = -expf(v.w);
  }
  float s[D_STATE];
  size_t ibase = (((size_t)b*32 + c)*D_MODEL + d)*D_STATE;
  #pragma unroll
  for (int n = 0; n < D_STATE; n += 4) {
    float4 v = *(const float4*)&sIn[ibase + n];
    s[n] = v.x; s[n+1] = v.y; s[n+2] = v.z; s[n+3] = v.w;
  }
  float dparam = Dp[d];
  __syncthreads();
  for (int j = 0; j < 64; j++) {
    size_t r = lbase + j;
    float dpv = dp[r*D_MODEL + d];
    float uv  = u[r*D_MODEL + d];
    float dbu = dpv * uv;
    float y = 0.f;
    #pragma unroll
    for (int n = 0; n < D_STATE; n++) {
      s[n] = __expf(a[n]*dpv)*s[n] + dbu*Bs[j][n];
      y += s[n]*Cs[j][n];
    }
    y += uv * dparam;
    float rr = xsres[r*1024 + D_MODEL + d];
    y *= rr/(1.f + __expf(-rr));       // silu(res)
    yout[r*D_MODEL + d] = f2bf(y);
  }
}

extern "C" void kernel_launch(void* const* d_in, const int* in_sizes, int n_in,
                              void* d_out, int out_size, void* d_ws, size_t ws_size,
                              hipStream_t stream)
{
  const float* atoms  = (const float*)d_in[0];
  const float* dis    = (const float*)d_in[1];
  const float* gpt    = (const float*)d_in[2];
  const float* fg     = (const float*)d_in[3];
  const float* inw    = (const float*)d_in[4];
  const float* convw  = (const float*)d_in[5];
  const float* convb  = (const float*)d_in[6];
  const float* xpw    = (const float*)d_in[7];
  const float* dtw    = (const float*)d_in[8];
  const float* dtb    = (const float*)d_in[9];
  const float* A_log  = (const float*)d_in[10];
  const float* Dparam = (const float*)d_in[11];
  const float* outw   = (const float*)d_in[12];
  const float* fw1    = (const float*)d_in[13];
  const float* fb1    = (const float*)d_in[14];
  const float* fw2    = (const float*)d_in[15];
  const float* fb2    = (const float*)d_in[16];

  char* ws = (char*)d_ws;
  size_t off = 0;
  auto alloc = [&](size_t bytes) { char* p = ws + off; off += (bytes + 255) & ~255ull; return p; };
  float* gb     = (float*)alloc((size_t)NBATCH*1024*4);
  float* hbuf   = (float*)alloc((size_t)NBATCH*512*4);
  u16*   xbf    = (u16*)  alloc((size_t)8192*512*2);          // later reused as y bf16
  u16*   inwbf  = (u16*)  alloc((size_t)1024*512*2);
  u16*   outwbf = (u16*)  alloc((size_t)512*512*2);
  u16*   wcomb  = (u16*)  alloc((size_t)640*512*2);
  u16*   disbf  = (u16*)  alloc((size_t)NBATCH*2048*2048*2);
  float* xsres  = (float*)alloc((size_t)8192*1024*4);
  float* dp     = (float*)alloc((size_t)8192*512*4);
  float* ubuf   = (float*)alloc((size_t)8192*512*4);
  u16*   ubf    = (u16*)  alloc((size_t)8192*512*2);
  float* Bv     = (float*)alloc((size_t)8192*16*4);
  float* Cv     = (float*)alloc((size_t)8192*16*4);
  u16*   deltaT = (u16*)  alloc((size_t)NBATCH*512*2048*2);
  float* slocal = (float*)alloc((size_t)NBATCH*32*512*16*4);
  float* sumdp  = (float*)alloc((size_t)NBATCH*32*512*4);
  float* sIn    = (float*)alloc((size_t)NBATCH*32*512*16*4);

  film1_kernel<<<dim3(32, NBATCH), 256, 0, stream>>>(gpt, fw1, fb1, hbuf);
  film2_kernel<<<dim3(64, NBATCH), 256, 0, stream>>>(hbuf, fw2, fb2, gb);
  xattn_kernel<<<dim3(SEQ/32, NBATCH), 256, 0, stream>>>(atoms, fg, gb, xbf);

  cvt_bf16_kernel<<<(1024*512/4)/256, 256, 0, stream>>>(inw, inwbf, 1024*512/4);
  cvt_bf16_kernel<<<(512*512/4)/256, 256, 0, stream>>>(outw, outwbf, 512*512/4);
  cvt_bf16_kernel<<<(NBATCH*2048*2048/4)/256, 256, 0, stream>>>(dis, disbf, NBATCH*2048*2048/4);
  build_wcomb_kernel<<<640, 256, 0, stream>>>(dtw, xpw, wcomb);

  // in_proj: [8192,512] @ [1024,512]^T -> xs_res
  gemm_bt_kernel<<<dim3(1024/128, 8192/128, 1), 256, 0, stream>>>(
      xbf, inwbf, xsres, 8192, 1024, 512, 0, 0, 0, 0);
  conv_silu_kernel<<<8192*128/256, 256, 0, stream>>>(xsres, convw, convb, ubuf, ubf);

  // fused delta/B/C: [8192,512] @ [640,512]^T, epilogue writes deltaT/Bv/Cv
  gemm_delta_kernel<<<dim3(640/128, 8192/128), 256, 0, stream>>>(
      ubf, wcomb, dtb, deltaT, Bv, Cv);

  // delta_p: per-batch [2048,2048] @ [512,2048]^T -> dp
  gemm_bt_kernel<<<dim3(512/128, 2048/128, NBATCH), 256, 0, stream>>>(
      disbf, deltaT, dp, 2048, 512, 2048,
      (long long)2048*2048, (long long)512*2048, (long long)2048*512, 0);

  scanA_kernel<<<dim3(2, 32, NBATCH), 256, 0, stream>>>(dp, ubuf, Bv, A_log, slocal, sumdp);
  scanB_kernel<<<32768/256, 256, 0, stream>>>(slocal, sumdp, A_log, sIn);
  u16* ybf = xbf;
  scanC_kernel<<<dim3(2, 32, NBATCH), 256, 0, stream>>>(dp, ubuf, Bv, Cv, A_log, Dparam, xsres, sIn, ybf);

  // out_proj: [8192,512] @ [512,512]^T -> out (with finite clamp)
  gemm_bt_kernel<<<dim3(512/128, 8192/128, 1), 256, 0, stream>>>(
      ybf, outwbf, (float*)d_out, 8192, 512, 512, 0, 0, 0, 1);
}